// Round 7
// baseline (548.137 us; speedup 1.0000x reference)
//
#include <hip/hip_runtime.h>
#include <hip/hip_bf16.h>
#include <cstdint>
#include <cstddef>

// ---------------------------------------------------------------------------
// SAGE GNN forward, bf16 MFMA 32x32x16, LDS-staged GEMM, BK=64.
//  - A tile [128][128B], XOR-swizzle byte^=(row&7)<<4; B pre-packed chunk-major
//  - T4 pipeline: 2 tiles in flight, counted vmcnt (never drain-0 mid-loop)
//  - aggregates: fully predicated batches (no serial tail)
// ---------------------------------------------------------------------------

typedef short bf16x8 __attribute__((ext_vector_type(8)));   // 8 bf16 = 4 VGPRs
typedef float f32x16 __attribute__((ext_vector_type(16)));

static inline int idiv_up(int a, int b) { return (a + b - 1) / b; }

static __device__ __forceinline__ float bf2f(unsigned short u) {
  union { unsigned int i; float f; } v; v.i = ((unsigned int)u) << 16; return v.f;
}
static __device__ __forceinline__ unsigned short f2bf(float f) {
  union { float f; unsigned int i; } v; v.f = f;
  return (unsigned short)((v.i + 0x7FFFu + ((v.i >> 16) & 1u)) >> 16);  // RNE
}
static __device__ __forceinline__ float lo16(unsigned int u) { return bf2f((unsigned short)(u & 0xffffu)); }
static __device__ __forceinline__ float hi16(unsigned int u) { return bf2f((unsigned short)(u >> 16)); }
static __device__ __forceinline__ unsigned int packbf(float a, float b) {
  return (unsigned int)f2bf(a) | ((unsigned int)f2bf(b) << 16);
}

// async global->LDS, 16B per lane. LDS dest: wave-uniform base + lane*16.
static __device__ __forceinline__ void gl_lds16(const void* g, void* l) {
  typedef __attribute__((address_space(3))) unsigned int lds_u32;
  typedef __attribute__((address_space(1))) const unsigned int glb_u32;
  __builtin_amdgcn_global_load_lds((glb_u32*)(uintptr_t)g,
                                   (lds_u32*)(unsigned int)(uintptr_t)l, 16, 0, 0);
}

template <int N> static __device__ __forceinline__ void wait_vmcnt() {
  if constexpr (N == 0)       asm volatile("s_waitcnt vmcnt(0)" ::: "memory");
  else if constexpr (N == 8)  asm volatile("s_waitcnt vmcnt(8)" ::: "memory");
  else if constexpr (N == 12) asm volatile("s_waitcnt vmcnt(12)" ::: "memory");
  else static_assert(N == 0 || N == 8 || N == 12, "unsupported vmcnt");
}

// ---------------- CSR build ----------------
__global__ void k_count_deg(const int* __restrict__ dst, int* __restrict__ deg, int E) {
  int e = blockIdx.x * blockDim.x + threadIdx.x;
  if (e < E) atomicAdd(deg + dst[e], 1);
}

// wave-shfl hierarchical scan, 1024 threads, chunked.
__global__ __launch_bounds__(1024)
void k_scan(const int* __restrict__ deg, int* __restrict__ row_off, int* __restrict__ cursor,
            float* __restrict__ deg_inv, int n) {
  __shared__ int wsum[16];
  const int tid = threadIdx.x;
  const int lane = tid & 63, wid = tid >> 6;
  int carry = 0;
  for (int base = 0; base < n; base += 1024) {
    const int i = base + tid;
    const int v = (i < n) ? deg[i] : 0;
    int incl = v;
#pragma unroll
    for (int off = 1; off < 64; off <<= 1) {
      int t = __shfl_up(incl, off);
      if (lane >= off) incl += t;
    }
    if (lane == 63) wsum[wid] = incl;
    __syncthreads();
    if (wid == 0) {
      int wv = (lane < 16) ? wsum[lane] : 0;
#pragma unroll
      for (int off = 1; off < 16; off <<= 1) {
        int t = __shfl_up(wv, off);
        if (lane >= off) wv += t;
      }
      if (lane < 16) wsum[lane] = wv;
    }
    __syncthreads();
    const int woff = (wid > 0) ? wsum[wid - 1] : 0;
    if (i < n) {
      const int ro = carry + woff + incl - v;
      row_off[i] = ro;
      cursor[i] = ro;
      deg_inv[i] = 1.0f / (float)((v > 1) ? v : 1);
    }
    const int tot = wsum[15];
    __syncthreads();
    carry += tot;
  }
  if (tid == 0) row_off[n] = carry;
}

__global__ void k_fill_csr(const int* __restrict__ src, const int* __restrict__ dst,
                           int* __restrict__ cursor, int* __restrict__ esrc, int E) {
  int e = blockIdx.x * blockDim.x + threadIdx.x;
  if (e < E) {
    int d = dst[e];
    int p = atomicAdd(cursor + d, 1);
    esrc[p] = src[e];
  }
}

// ---------------- x: f32 -> bf16 plain conversion --------------------------
__global__ __launch_bounds__(256)
void k_conv_x(const float* __restrict__ src, unsigned short* __restrict__ dst, int n4) {
  for (int i = blockIdx.x * blockDim.x + threadIdx.x; i < n4; i += gridDim.x * blockDim.x) {
    const float4 v = *((const float4*)src + i);
    uint2 o;
    o.x = packbf(v.x, v.y);
    o.y = packbf(v.z, v.w);
    *((uint2*)dst + i) = o;
  }
}

// ---------------- weights: f32 -> bf16 packed chunk-major ------------------
// dst elem index = kt64*(O*64) + chunk*(O*8) + col*8 + j  holds
// src[col][kt64*64 + chunk*8 + j]  (chunk in 0..7)
struct PackJob { const float* src; unsigned short* dst; int O; int K; };
struct PackJobs { PackJob j[10]; };

__global__ __launch_bounds__(256)
void k_pack_w(PackJobs jobs) {
  const PackJob J = jobs.j[blockIdx.y];
  const int total = J.O * J.K / 2;  // u32 outputs
  const int OK64 = J.O * 64;
  for (int u = blockIdx.x * blockDim.x + threadIdx.x; u < total; u += gridDim.x * blockDim.x) {
    const int e = u * 2;
    const int kt = e / OK64;
    const int rem = e - kt * OK64;
    const int chunk = rem / (J.O * 8);
    const int rem2 = rem - chunk * (J.O * 8);
    const int col = rem2 >> 3;
    const int j = rem2 & 7;
    const int korig = kt * 64 + chunk * 8 + j;
    const float f0 = J.src[(size_t)col * J.K + korig];
    const float f1 = J.src[(size_t)col * J.K + korig + 1];
    ((unsigned int*)J.dst)[u] = packbf(f0, f1);
  }
}

// ---------------- mean aggregation, bf16 in/out, f32 accum -----------------
// Fully predicated batches: tail edges load in the same parallel batch
// (clamped index), accumulate masked. No serial dependent-latency tail.
__global__ __launch_bounds__(256)
void k_agg128(const unsigned short* __restrict__ h, const int* __restrict__ row_off,
              const int* __restrict__ esrc, const float* __restrict__ deg_inv,
              unsigned short* __restrict__ agg, int N) {
  const int node = blockIdx.x * 4 + (threadIdx.x >> 6);
  if (node >= N) return;
  const int lane = threadIdx.x & 63;
  const int s0 = row_off[node], s1 = row_off[node + 1];
  const unsigned int* hp = (const unsigned int*)h;
  float al = 0.f, ah = 0.f;
  for (int i = s0; i < s1; i += 8) {
    unsigned int u[8];
#pragma unroll
    for (int j = 0; j < 8; ++j) {
      const int e = (i + j < s1) ? (i + j) : i;
      u[j] = hp[(size_t)esrc[e] * 64 + lane];
    }
#pragma unroll
    for (int j = 0; j < 8; ++j)
      if (i + j < s1) { al += lo16(u[j]); ah += hi16(u[j]); }
  }
  const float di = deg_inv[node];
  ((unsigned int*)agg)[(size_t)node * 64 + lane] = packbf(al * di, ah * di);
}

__global__ __launch_bounds__(256)
void k_agg256(const unsigned short* __restrict__ h, const int* __restrict__ row_off,
              const int* __restrict__ esrc, const float* __restrict__ deg_inv,
              unsigned short* __restrict__ agg, int N) {
  const int node = blockIdx.x * 4 + (threadIdx.x >> 6);
  if (node >= N) return;
  const int lane = threadIdx.x & 63;
  const int s0 = row_off[node], s1 = row_off[node + 1];
  const unsigned int* hp = (const unsigned int*)h;
  float al = 0.f, ah = 0.f, bl_ = 0.f, bh = 0.f;
  for (int i = s0; i < s1; i += 4) {
    unsigned int u0[4], u1[4];
#pragma unroll
    for (int j = 0; j < 4; ++j) {
      const int e = (i + j < s1) ? (i + j) : i;
      const size_t b = (size_t)esrc[e] * 128;
      u0[j] = hp[b + lane];
      u1[j] = hp[b + 64 + lane];
    }
#pragma unroll
    for (int j = 0; j < 4; ++j)
      if (i + j < s1) {
        al += lo16(u0[j]); ah += hi16(u0[j]);
        bl_ += lo16(u1[j]); bh += hi16(u1[j]);
      }
  }
  const float di = deg_inv[node];
  unsigned int* ap = (unsigned int*)agg;
  ap[(size_t)node * 128 + lane] = packbf(al * di, ah * di);
  ap[(size_t)node * 128 + 64 + lane] = packbf(bl_ * di, bh * di);
}

__global__ __launch_bounds__(256)
void k_agg64(const unsigned short* __restrict__ h, const int* __restrict__ row_off,
             const int* __restrict__ esrc, const float* __restrict__ deg_inv,
             unsigned short* __restrict__ agg, int N) {
  const int node = blockIdx.x * 4 + (threadIdx.x >> 6);
  if (node >= N) return;
  const int lane = threadIdx.x & 63;
  const int half = lane >> 5, c = lane & 31;
  const int s0 = row_off[node], s1 = row_off[node + 1];
  const unsigned int* hp = (const unsigned int*)h;
  float al = 0.f, ah = 0.f;
  for (int i = s0 + half; i < s1; i += 8) {  // this half: i, i+2, i+4, i+6
    unsigned int u[4];
#pragma unroll
    for (int j = 0; j < 4; ++j) {
      const int idx = i + 2 * j;
      const int e = (idx < s1) ? idx : i;
      u[j] = hp[(size_t)esrc[e] * 32 + c];
    }
#pragma unroll
    for (int j = 0; j < 4; ++j)
      if (i + 2 * j < s1) { al += lo16(u[j]); ah += hi16(u[j]); }
  }
  al += __shfl_xor(al, 32);
  ah += __shfl_xor(ah, 32);
  if (half == 0) {
    const float di = deg_inv[node];
    ((unsigned int*)agg)[(size_t)node * 32 + c] = packbf(al * di, ah * di);
  }
}

// ---------------- fused SAGE GEMM: C = relu(A0@B0p^T + A1@B1p^T + bias) ----
// Block: 128 rows x BN=WC*64 cols; 2 x WC waves; MFMA 32x32x16; BK=64.
// LDS/buf: A[128][128B] swizzled (16KB) + B[8][BN][16B] chunk-major (BN*128B).
// T4 pipeline: tiles t and t+1 in flight; wait vmcnt(LPT) at tile top.
template <int WC>
__global__ __launch_bounds__(WC * 128)
void k_sage_gemm(const unsigned short* __restrict__ A0, const unsigned short* __restrict__ B0,
                 const unsigned short* __restrict__ A1, const unsigned short* __restrict__ B1,
                 const float* __restrict__ bias, unsigned short* __restrict__ C,
                 int Nn, int K, int O) {
  constexpr int BN = WC * 64;
  constexpr int T = WC * 128;
  constexpr int ACH = 1024;            // A 16B-chunks per tile (128 rows x 8)
  constexpr int BCH = BN * 8;          // B 16B-chunks per tile
  constexpr int LPT = (ACH + BCH) / T; // chunks per thread per stage
  constexpr int BSH = (WC == 1) ? 6 : ((WC == 2) ? 7 : 8);  // log2(BN)
  constexpr int LDSBUF = 16384 + BN * 128;
  __shared__ char lds[2 * LDSBUF];

  const int tid = threadIdx.x;
  const int w = tid >> 6, lane = tid & 63;
  const int wr = w / WC, wc = w % WC;
  const int fr = lane & 31, fq = lane >> 5;
  const int row0 = blockIdx.x * 128 + wr * 64;
  const int colb = blockIdx.y * BN;

  const int KT0 = K >> 6;        // 64-wide tiles per phase
  const int NT = 2 * KT0;

  f32x16 acc[2][2];
#pragma unroll
  for (int m = 0; m < 2; ++m)
#pragma unroll
    for (int cn = 0; cn < 2; ++cn)
#pragma unroll
      for (int r = 0; r < 16; ++r) acc[m][cn][r] = 0.f;

  auto stage = [&](int buf, int t) {
    const int ph = (t >= KT0) ? 1 : 0;
    const unsigned short* Ab = ph ? A1 : A0;
    const unsigned short* Bb = ph ? B1 : B0;
    const int ktl = t - ph * KT0;
    char* lb = lds + buf * LDSBUF;
#pragma unroll
    for (int i = 0; i < LPT; ++i) {
      const int ch = tid + i * T;
      if (ch < ACH) {
        const int ar = ch >> 3, s = ch & 7;         // LDS row, slot
        int g = blockIdx.x * 128 + ar;
        if (g >= Nn) g = Nn - 1;
        // inverse-swizzled global source; linear LDS dest
        gl_lds16(Ab + (size_t)g * K + ktl * 64 + ((s ^ (ar & 7)) << 3), lb + ch * 16);
      } else {
        const int cb = ch - ACH;
        const int chunk = cb >> BSH, colrel = cb & (BN - 1);
        gl_lds16(Bb + (size_t)ktl * O * 64 + chunk * O * 8 + (colb + colrel) * 8,
                 lb + 16384 + cb * 16);
      }
    }
  };

  stage(0, 0);
  stage(1, 1);
#pragma unroll 1
  for (int t = 0; t < NT; ++t) {
    if (t + 1 < NT) wait_vmcnt<LPT>();   // drain tile t, keep t+1 in flight
    else            wait_vmcnt<0>();
    __syncthreads();
    const char* lb = lds + (t & 1) * LDSBUF;
#pragma unroll
    for (int k16i = 0; k16i < 4; ++k16i) {
      const int c = k16i * 2 + fq;                  // chunk 0..7
      bf16x8 af[2], bg[2];
#pragma unroll
      for (int m = 0; m < 2; ++m) {
        const int rl = wr * 64 + m * 32 + fr;
        af[m] = *(const bf16x8*)(lb + rl * 128 + ((c ^ (rl & 7)) << 4));
      }
#pragma unroll
      for (int cn = 0; cn < 2; ++cn) {
        const int colrel = wc * 64 + cn * 32 + fr;
        bg[cn] = *(const bf16x8*)(lb + 16384 + c * (BN * 16) + colrel * 16);
      }
#pragma unroll
      for (int m = 0; m < 2; ++m)
#pragma unroll
        for (int cn = 0; cn < 2; ++cn)
          acc[m][cn] = __builtin_amdgcn_mfma_f32_32x32x16_bf16(af[m], bg[cn], acc[m][cn], 0, 0, 0);
    }
    if (t + 2 < NT) {
      __syncthreads();                  // all waves done reading buf[t&1]
      stage(t & 1, t + 2);
    }
  }

  // epilogue. C/D map: col = lane&31, row = (reg&3) + 8*(reg>>2) + 4*(lane>>5).
#pragma unroll
  for (int cn = 0; cn < 2; ++cn) {
    const int col = colb + wc * 64 + cn * 32 + fr;
    const float bb = bias[col];
#pragma unroll
    for (int m = 0; m < 2; ++m) {
#pragma unroll
      for (int reg = 0; reg < 16; ++reg) {
        const float v = fmaxf(acc[m][cn][reg] + bb, 0.f);
        const float nb = __shfl_xor(v, 1);
        const int row = row0 + m * 32 + (reg & 3) + 8 * (reg >> 2) + 4 * fq;
        if (!(lane & 1) && row < Nn) {
          *(unsigned int*)(C + (size_t)row * O + col) = packbf(v, nb);
        }
      }
    }
  }
}

// ---------------- head: logits(512->4) + softmax, 4 waves per block --------
__global__ __launch_bounds__(256)
void k_out_softmax(const unsigned short* __restrict__ h, const float* __restrict__ W4,
                   const float* __restrict__ b, float* __restrict__ out, int N) {
  const int n = blockIdx.x * 4 + (threadIdx.x >> 6);
  if (n >= N) return;
  const int lane = threadIdx.x & 63;
  const unsigned int* hp = (const unsigned int*)h + (size_t)n * 256;
  float a[4] = {0.f, 0.f, 0.f, 0.f};
#pragma unroll
  for (int it = 0; it < 4; ++it) {
    const unsigned int v = hp[it * 64 + lane];
    const float lo = lo16(v);
    const float hi = hi16(v);
    const int k = (it * 64 + lane) * 2;
#pragma unroll
    for (int c = 0; c < 4; ++c)
      a[c] += lo * W4[c * 512 + k] + hi * W4[c * 512 + k + 1];
  }
#pragma unroll
  for (int off = 32; off > 0; off >>= 1) {
#pragma unroll
    for (int c = 0; c < 4; ++c) a[c] += __shfl_down(a[c], off);
  }
  if (lane == 0) {
    const float l0 = a[0] + b[0], l1 = a[1] + b[1], l2 = a[2] + b[2], l3 = a[3] + b[3];
    const float m = fmaxf(fmaxf(l0, l1), fmaxf(l2, l3));
    const float e0 = expf(l0 - m), e1 = expf(l1 - m), e2 = expf(l2 - m), e3 = expf(l3 - m);
    const float inv = 1.0f / (e0 + e1 + e2 + e3);
    float4 r; r.x = e0 * inv; r.y = e1 * inv; r.z = e2 * inv; r.w = e3 * inv;
    *(float4*)(out + (size_t)n * 4) = r;
  }
}

// ---------------------------------------------------------------------------
extern "C" void kernel_launch(void* const* d_in, const int* in_sizes, int n_in,
                              void* d_out, int out_size, void* d_ws, size_t ws_size,
                              hipStream_t stream) {
  const float* x = (const float*)d_in[0];
  const float* Wl[5] = {(const float*)d_in[1], (const float*)d_in[4], (const float*)d_in[7],
                        (const float*)d_in[10], (const float*)d_in[13]};
  const float* bl[5] = {(const float*)d_in[2], (const float*)d_in[5], (const float*)d_in[8],
                        (const float*)d_in[11], (const float*)d_in[14]};
  const float* Wr[5] = {(const float*)d_in[3], (const float*)d_in[6], (const float*)d_in[9],
                        (const float*)d_in[12], (const float*)d_in[15]};
  const float* Wout = (const float*)d_in[16];
  const float* bout = (const float*)d_in[17];
  const int* eidx = (const int*)d_in[18];

  const int N = in_sizes[0] / 128;
  const int E = in_sizes[18] / 2;
  const int* srcI = eidx;
  const int* dstI = eidx + E;

  const int Kd[5] = {128, 128, 64, 128, 256};
  const int Od[5] = {128, 64, 128, 256, 512};

  // workspace carve-out (256B aligned)
  char* ws = (char*)d_ws;
  size_t p = 0;
  auto alloc = [&](size_t bytes) { size_t r = p; p += (bytes + 255) & ~(size_t)255; return r; };
  int*   deg     = (int*)(ws + alloc((size_t)N * 4));
  int*   row_off = (int*)(ws + alloc((size_t)(N + 1) * 4));
  int*   cursor  = (int*)(ws + alloc((size_t)N * 4));
  float* deg_inv = (float*)(ws + alloc((size_t)N * 4));
  int*   esrc    = (int*)(ws + alloc((size_t)E * 4));
  unsigned short* xb = (unsigned short*)(ws + alloc((size_t)N * 128 * 2));
  unsigned short* wlb[5];
  unsigned short* wrb[5];
  for (int l = 0; l < 5; ++l) {
    wlb[l] = (unsigned short*)(ws + alloc((size_t)Od[l] * Kd[l] * 2));
    wrb[l] = (unsigned short*)(ws + alloc((size_t)Od[l] * Kd[l] * 2));
  }
  unsigned short* bufA = (unsigned short*)(ws + alloc((size_t)N * 512 * 2));
  unsigned short* bufB = (unsigned short*)(ws + alloc((size_t)N * 256 * 2));
  unsigned short* agg  = (unsigned short*)(ws + alloc((size_t)N * 256 * 2));
  (void)ws_size; (void)n_in; (void)out_size;

  // ---- conversions: x plain; weights packed chunk-major ----
  k_conv_x<<<128, 256, 0, stream>>>(x, xb, N * 128 / 4);
  PackJobs jobs;
  for (int l = 0; l < 5; ++l) {
    jobs.j[2 * l]     = {Wl[l], wlb[l], Od[l], Kd[l]};
    jobs.j[2 * l + 1] = {Wr[l], wrb[l], Od[l], Kd[l]};
  }
  k_pack_w<<<dim3(32, 10), 256, 0, stream>>>(jobs);

  // ---- CSR build ----
  hipMemsetAsync(deg, 0, (size_t)N * 4, stream);
  k_count_deg<<<idiv_up(E, 256), 256, 0, stream>>>(dstI, deg, E);
  k_scan<<<1, 1024, 0, stream>>>(deg, row_off, cursor, deg_inv, N);
  k_fill_csr<<<idiv_up(E, 256), 256, 0, stream>>>(srcI, dstI, cursor, esrc, E);

  unsigned short* houts[5] = {bufA, bufB, bufA, bufB, bufA};

  const unsigned short* hin = xb;
  for (int l = 0; l < 5; ++l) {
    const int K = Kd[l], O = Od[l];
    // aggregate
    if (K == 64)
      k_agg64<<<idiv_up(N, 4), 256, 0, stream>>>(hin, row_off, esrc, deg_inv, agg, N);
    else if (K == 128)
      k_agg128<<<idiv_up(N, 4), 256, 0, stream>>>(hin, row_off, esrc, deg_inv, agg, N);
    else
      k_agg256<<<idiv_up(N, 4), 256, 0, stream>>>(hin, row_off, esrc, deg_inv, agg, N);

    // fused GEMM + bias + relu
    unsigned short* hout = houts[l];
    const int gx = idiv_up(N, 128);
    switch (l) {
      case 0:  // K=128, O=128: WC=2
        k_sage_gemm<2><<<dim3(gx, 1), 256, 0, stream>>>(agg, wlb[l], hin, wrb[l], bl[l], hout, N, K, O);
        break;
      case 1:  // K=128, O=64: WC=1
        k_sage_gemm<1><<<dim3(gx, 1), 128, 0, stream>>>(agg, wlb[l], hin, wrb[l], bl[l], hout, N, K, O);
        break;
      case 2:  // K=64, O=128: WC=2
        k_sage_gemm<2><<<dim3(gx, 1), 256, 0, stream>>>(agg, wlb[l], hin, wrb[l], bl[l], hout, N, K, O);
        break;
      case 3:  // K=128, O=256: WC=2, col-split x2
        k_sage_gemm<2><<<dim3(gx, 2), 256, 0, stream>>>(agg, wlb[l], hin, wrb[l], bl[l], hout, N, K, O);
        break;
      default: // K=256, O=512: WC=2, col-split x4
        k_sage_gemm<2><<<dim3(gx, 4), 256, 0, stream>>>(agg, wlb[l], hin, wrb[l], bl[l], hout, N, K, O);
        break;
    }
    hin = hout;
  }
  k_out_softmax<<<idiv_up(N, 4), 256, 0, stream>>>(hin, Wout, bout, (float*)d_out, N);
}